// Round 19
// baseline (25.574 us; speedup 1.0000x reference)
//
#include <hip/hip_runtime.h>
#include <hip/hip_bf16.h>

typedef __bf16 bf16x8 __attribute__((ext_vector_type(8)));
typedef float  f32x4  __attribute__((ext_vector_type(4)));
typedef int    int8v  __attribute__((ext_vector_type(8)));

#define UBV   35.0f
#define SUMC  150.0f
#define SCL1  0x7f7f7f7f   // 4x e8m0 scale = 1.0 per 32-elem block

__device__ __forceinline__ float lrelu(float x) { return fmaxf(x, 0.2f * x); }

__device__ __forceinline__ unsigned pkword(float a, float b, float c, float d) {
    unsigned w = (unsigned)__builtin_amdgcn_cvt_pk_fp8_f32(a, b, 0, false);
    w = (unsigned)__builtin_amdgcn_cvt_pk_fp8_f32(c, d, (int)w, true);
    return w;
}
__device__ __forceinline__ long mk64(unsigned lo, unsigned hi) {
    return (long)(((unsigned long long)hi << 32) | (unsigned long long)lo);
}
__device__ __forceinline__ void async16(void* lds_uniform, const void* gsrc) {
    __builtin_amdgcn_global_load_lds(
        (__attribute__((address_space(1))) void*)(gsrc),
        (__attribute__((address_space(3))) void*)(lds_uniform),
        16, 0, 0);
}

// ---------------------------------------------------------------------------
// prep: R17 MX sigma mapping (verified absmax 0.125) + NEW sfrag emitter:
// state pre-packed as bf16 A-fragments [tile][lane][8] with bias carrier
// k=17 := 1.0 baked in. Written per replay -> L2-warm for the actor.
// ---------------------------------------------------------------------------

__global__ void prep_kernel(const float* __restrict__ state,
                            const float* __restrict__ W1, const float* __restrict__ b1,
                            const float* __restrict__ W2, const float* __restrict__ b2,
                            const float* __restrict__ W3, const float* __restrict__ b3,
                            __bf16* __restrict__ w1p, uint2* __restrict__ w2p,
                            uint2* __restrict__ w3c, __bf16* __restrict__ sfrag)
{
    int idx = blockIdx.x * blockDim.x + threadIdx.x;
    if (idx < 1664) {
        int lane = idx & 63;
        int nt = idx >> 6;
        int rho = lane & 15, g = lane >> 4;
        int kap = (nt < 24)
            ? 128 * (nt >> 3) + 32 * (rho >> 2) + 4 * (nt & 7) + (rho & 3)
            : 384 + 8 * (rho >> 2) + 4 * (nt & 1) + (rho & 3);
        bf16x8 v;
        #pragma unroll
        for (int j = 0; j < 8; ++j) {
            int k = g * 8 + j;
            float x = 0.f;
            if (kap < 400) {
                if (k < 17) x = W1[kap * 17 + k];
                else if (k == 17) x = b1[kap];
            } else if (kap == 400) {
                if (k == 17) x = 1.0f;
            }
            v[j] = (__bf16)x;
        }
        *(bf16x8*)(w1p + idx * 8) = v;
    } else if (idx < 1664 + 16640) {
        int i2 = idx - 1664;
        int fg = i2 >> 6, lane = i2 & 63;
        int q = fg / 65, rem = fg % 65;
        int t = rem / 13, kt = rem % 13;
        int c16 = lane & 15, g = lane >> 4;
        int local = t * 16 + c16;
        int ff = q * 79 + local;
        int within, kbase;
        if (kt < 12) {
            int m = kt >> 2, u = kt & 3;
            kbase = 128 * m + 32 * g + 8 * u;
            within = m * 256 + lane * 4 + u;
        } else {
            kbase = 384 + g * 8;
            within = 768 + lane;
        }
        float v[8];
        #pragma unroll
        for (int j = 0; j < 8; ++j) {
            int kap = kbase + j;
            float x = 0.f;
            if (local == 79) {
                x = (kap == 400) ? 1.0f : 0.f;
            } else if (local < 79 && ff < 300) {
                if (kap < 400) x = W2[ff * 400 + kap];
                else if (kap == 400) x = b2[ff];
            }
            v[j] = x;
        }
        uint2 d;
        d.x = pkword(v[0], v[1], v[2], v[3]);
        d.y = pkword(v[4], v[5], v[6], v[7]);
        w2p[(q * 5 + t) * 832 + within] = d;
    } else if (idx < 1664 + 16640 + 768) {
        int i3 = idx - 1664 - 16640;
        int fg = i3 >> 6, lane = i3 & 63;
        int q = fg / 3, k2 = fg % 3;
        int o = lane & 15, g = lane >> 4;
        float v[8];
        #pragma unroll
        for (int j = 0; j < 8; ++j) {
            int t2  = 2 * k2 + (j >> 2);
            int rho = g * 4 + (j & 3);
            int local = t2 * 16 + rho;
            float x = 0.f;
            if (o < 5 && t2 < 5) {
                if (local == 79) x = b3[o] * 0.25f;
                else if (local < 79 && q * 79 + local < 300)
                    x = W3[o * 300 + q * 79 + local];
            }
            v[j] = x;
        }
        uint2 d;
        d.x = pkword(v[0], v[1], v[2], v[3]);
        d.y = pkword(v[4], v[5], v[6], v[7]);
        w3c[i3] = d;
    } else if (idx < 1664 + 16640 + 768 + 262144) {
        // state A-fragments: tile in [0,4096), lane (c16,g): row=tile*16+c16,
        // k=g*8+j; k==17 -> 1.0 (bias carrier), k>17 -> 0. Same rounding as
        // the old in-actor pack -> bit-identical numerics.
        int i4 = idx - 19072;
        int tile = i4 >> 6, lane = i4 & 63;
        int c16 = lane & 15, g = lane >> 4;
        const float* sp = state + (tile * 16 + c16) * 17;
        bf16x8 v;
        #pragma unroll
        for (int j = 0; j < 8; ++j) {
            int k = g * 8 + j;
            float x = (k < 17) ? sp[k] : (k == 17 ? 1.0f : 0.f);
            v[j] = (__bf16)x;
        }
        *(bf16x8*)(sfrag + i4 * 8) = v;
    }
}

// ---------------------------------------------------------------------------
// Actor R19: R18 structure (256 blocks x 512 thr, 8 waves dual m-tile,
// whole W2p in LDS, ONE barrier, independent waves) with phase A fed by
// prep-packed L2-warm state fragments: 2 aligned b128 loads per lane,
// zero branches (was 17 scalar 4B loads + g-conditionals from cold HBM).
// ---------------------------------------------------------------------------
__global__ __launch_bounds__(512, 2)
void actor_kernel(const __bf16* __restrict__ sfrag,
                  const __bf16* __restrict__ w1p,
                  const uint2* __restrict__ w2p,
                  const uint2* __restrict__ w3c,
                  float* __restrict__ out)
{
    __shared__ __align__(32) char s_w2[133120];   // entire W2p, read-only after B1

    const int tid = threadIdx.x;
    const int wid = tid >> 6;            // 8 waves: rows wid*32..+31
    const int ln  = tid & 63;
    const int brow = (blockIdx.x << 8) + wid * 32;   // 256 rows/block

    // ---- state A-frags first (VGPR dests, want in flight earliest) ----
    const int tileA = (blockIdx.x << 4) + wid * 2;
    bf16x8 sbA = *(const bf16x8*)(sfrag + (tileA * 64 + ln) * 8);
    bf16x8 sbB = *(const bf16x8*)(sfrag + ((tileA + 1) * 64 + ln) * 8);

    // ---- stage ALL W2p -> LDS (130 x 1KB chunks, 8-wave stride) ----
    {
        const char* gb = (const char*)w2p;
        for (int i = wid; i < 130; i += 8)
            async16(s_w2 + i * 1024, gb + i * 1024 + ln * 16);
    }

    // ---- hoisted W3 fragment loads (L2-hot) ----
    long w3r[4][3];
    {
        const long* gw3 = (const long*)w3c;
        #pragma unroll
        for (int q = 0; q < 4; ++q)
            #pragma unroll
            for (int k2 = 0; k2 < 3; ++k2)
                w3r[q][k2] = gw3[(q * 3 + k2) * 64 + ln];
    }

    // ---- Phase A from L2-resident w1p: h1 as MX B-frags + K=32 tail ----
    int8v fmA[3], fmB[3];
    long fr12A, fr12B;
    {
        #pragma unroll
        for (int m = 0; m < 3; ++m)
            #pragma unroll
            for (int j = 0; j < 8; ++j) {
                int nt = m * 8 + j;
                bf16x8 w = *(const bf16x8*)(w1p + (nt * 64 + ln) * 8);
                f32x4 aA = {0.f,0.f,0.f,0.f}, aB = {0.f,0.f,0.f,0.f};
                aA = __builtin_amdgcn_mfma_f32_16x16x32_bf16(w, sbA, aA, 0, 0, 0);
                aB = __builtin_amdgcn_mfma_f32_16x16x32_bf16(w, sbB, aB, 0, 0, 0);
                fmA[m][j] = (int)pkword(lrelu(aA[0]), lrelu(aA[1]), lrelu(aA[2]), lrelu(aA[3]));
                fmB[m][j] = (int)pkword(lrelu(aB[0]), lrelu(aB[1]), lrelu(aB[2]), lrelu(aB[3]));
            }
        unsigned dA[2], dB[2];
        #pragma unroll
        for (int h = 0; h < 2; ++h) {
            int nt = 24 + h;
            bf16x8 w = *(const bf16x8*)(w1p + (nt * 64 + ln) * 8);
            f32x4 aA = {0.f,0.f,0.f,0.f}, aB = {0.f,0.f,0.f,0.f};
            aA = __builtin_amdgcn_mfma_f32_16x16x32_bf16(w, sbA, aA, 0, 0, 0);
            aB = __builtin_amdgcn_mfma_f32_16x16x32_bf16(w, sbB, aB, 0, 0, 0);
            dA[h] = pkword(lrelu(aA[0]), lrelu(aA[1]), lrelu(aA[2]), lrelu(aA[3]));
            dB[h] = pkword(lrelu(aB[0]), lrelu(aB[1]), lrelu(aB[2]), lrelu(aB[3]));
        }
        fr12A = mk64(dA[0], dA[1]);
        fr12B = mk64(dB[0], dB[1]);
    }

    __syncthreads();   // THE barrier: W2 staged; nothing syncs after

    // ---- 4 quarters, fully independent per wave (LDS read-only) ----
    f32x4 ccsA = {0.f, 0.f, 0.f, 0.f};
    f32x4 ccsB = {0.f, 0.f, 0.f, 0.f};

    #pragma unroll 1
    for (int q = 0; q < 4; ++q) {
        const char* bufp = s_w2 + q * 33280;
        unsigned wdA[5], wdB[5];
        #pragma unroll
        for (int t = 0; t < 5; ++t) {
            const char* bt = bufp + t * 6656;
            f32x4 aA = {0.f,0.f,0.f,0.f}, aB = {0.f,0.f,0.f,0.f};
            #pragma unroll
            for (int m = 0; m < 3; ++m) {
                int8v wf = *(const int8v*)(bt + m * 2048 + ln * 32);
                aA = __builtin_amdgcn_mfma_scale_f32_16x16x128_f8f6f4(
                         wf, fmA[m], aA, 0, 0, 0, SCL1, 0, SCL1);
                aB = __builtin_amdgcn_mfma_scale_f32_16x16x128_f8f6f4(
                         wf, fmB[m], aB, 0, 0, 0, SCL1, 0, SCL1);
            }
            long p12 = *(const long*)(bt + 6144 + ln * 8);
            aA = __builtin_amdgcn_mfma_f32_16x16x32_fp8_fp8(p12, fr12A, aA, 0, 0, 0);
            aB = __builtin_amdgcn_mfma_f32_16x16x32_fp8_fp8(p12, fr12B, aB, 0, 0, 0);
            wdA[t] = pkword(lrelu(aA[0]), lrelu(aA[1]), lrelu(aA[2]), lrelu(aA[3]));
            wdB[t] = pkword(lrelu(aB[0]), lrelu(aB[1]), lrelu(aB[2]), lrelu(aB[3]));
        }
        {
            f32x4 cc = {0.f, 0.f, 0.f, 0.f};
            cc = __builtin_amdgcn_mfma_f32_16x16x32_fp8_fp8(w3r[q][0], mk64(wdA[0], wdA[1]), cc, 0, 0, 0);
            cc = __builtin_amdgcn_mfma_f32_16x16x32_fp8_fp8(w3r[q][1], mk64(wdA[2], wdA[3]), cc, 0, 0, 0);
            cc = __builtin_amdgcn_mfma_f32_16x16x32_fp8_fp8(w3r[q][2], mk64(wdA[4], 0u),     cc, 0, 0, 0);
            ccsA += cc;
        }
        {
            f32x4 cc = {0.f, 0.f, 0.f, 0.f};
            cc = __builtin_amdgcn_mfma_f32_16x16x32_fp8_fp8(w3r[q][0], mk64(wdB[0], wdB[1]), cc, 0, 0, 0);
            cc = __builtin_amdgcn_mfma_f32_16x16x32_fp8_fp8(w3r[q][1], mk64(wdB[2], wdB[3]), cc, 0, 0, 0);
            cc = __builtin_amdgcn_mfma_f32_16x16x32_fp8_fp8(w3r[q][2], mk64(wdB[4], 0u),     cc, 0, 0, 0);
            ccsB += cc;
        }
    }

    // ---- Epilogue: 32 lanes/wave solve QP for 32 rows ----
    float tA4 = __shfl_xor(ccsA[0], 16);
    float sB0 = __shfl_xor(ccsB[0], 16);
    float sB1 = __shfl_xor(ccsB[1], 16);
    float sB2 = __shfl_xor(ccsB[2], 16);
    float sB3 = __shfl_xor(ccsB[3], 16);

    if (ln < 32) {
        float v[5];
        if (ln < 16) {
            v[0] = -lrelu(ccsA[0]); v[1] = -lrelu(ccsA[1]);
            v[2] = -lrelu(ccsA[2]); v[3] = -lrelu(ccsA[3]);
            v[4] = -lrelu(tA4);
        } else {
            v[0] = -lrelu(sB0); v[1] = -lrelu(sB1);
            v[2] = -lrelu(sB2); v[3] = -lrelu(sB3);
            v[4] = -lrelu(ccsB[0]);
        }

        float bp[10];
        #pragma unroll
        for (int i = 0; i < 5; ++i) { bp[i] = v[i]; bp[i + 5] = v[i] - UBV; }
        float blo = -1e30f, glo = 0.f;
        #pragma unroll
        for (int j = 0; j < 10; ++j) {
            float b = bp[j];
            float gsum = 0.f;
            #pragma unroll
            for (int i = 0; i < 5; ++i) {
                float zc = v[i] - b;
                zc = fminf(fmaxf(zc, 0.f), UBV);
                gsum += zc;
            }
            if (gsum >= SUMC && b > blo) { blo = b; glo = gsum; }
        }
        float bhi = 1e30f;
        #pragma unroll
        for (int j = 0; j < 10; ++j) {
            float b = bp[j];
            if (b > blo && b < bhi) bhi = b;
        }
        float mid = 0.5f * (blo + bhi);
        int nfree = 0;
        #pragma unroll
        for (int i = 0; i < 5; ++i)
            nfree += (v[i] > mid && v[i] < mid + UBV) ? 1 : 0;
        float nu = (nfree > 0) ? blo + (glo - SUMC) / (float)nfree : blo;

        int row = brow + ln;
        #pragma unroll
        for (int o = 0; o < 5; ++o) {
            float zf = v[o] - nu;
            zf = fminf(fmaxf(zf, 0.f), UBV);
            out[row * 5 + o] = zf;
        }
    }
}

extern "C" void kernel_launch(void* const* d_in, const int* in_sizes, int n_in,
                              void* d_out, int out_size, void* d_ws, size_t ws_size,
                              hipStream_t stream) {
    const float* state = (const float*)d_in[0];
    const float* W1    = (const float*)d_in[1];
    const float* b1    = (const float*)d_in[2];
    const float* W2    = (const float*)d_in[3];
    const float* b2    = (const float*)d_in[4];
    const float* W3    = (const float*)d_in[5];
    const float* b3    = (const float*)d_in[6];
    float* out = (float*)d_out;

    char* base = (char*)d_ws;
    __bf16* w1p   = (__bf16*)base;                    // 26,624B
    uint2*  w2p   = (uint2*)(base + 26624);           // 133,120B
    uint2*  w3c   = (uint2*)(base + 26624 + 133120);  // 6,144B
    __bf16* sfrag = (__bf16*)(base + 165888);         // 4,194,304B state frags

    int B = in_sizes[0] / 17;                         // 65536
    const int total = 1664 + 16640 + 768 + (B / 16) * 64;   // 281,216
    prep_kernel<<<(total + 255) / 256, 256, 0, stream>>>(state, W1, b1, W2, b2,
                                                         W3, b3, w1p, w2p, w3c,
                                                         sfrag);

    actor_kernel<<<B / 256, 512, 0, stream>>>(sfrag, w1p, w2p, w3c, out);
}

// Round 20
// 24.673 us; speedup vs baseline: 1.0365x; 1.0365x over previous
//
#include <hip/hip_runtime.h>
#include <hip/hip_bf16.h>

typedef __bf16 bf16x8 __attribute__((ext_vector_type(8)));
typedef float  f32x4  __attribute__((ext_vector_type(4)));
typedef int    int8v  __attribute__((ext_vector_type(8)));

#define UBV   35.0f
#define SUMC  150.0f
#define SCL1  0x7f7f7f7f   // 4x e8m0 scale = 1.0 per 32-elem block

__device__ __forceinline__ float lrelu(float x) { return fmaxf(x, 0.2f * x); }

__device__ __forceinline__ unsigned pkword(float a, float b, float c, float d) {
    unsigned w = (unsigned)__builtin_amdgcn_cvt_pk_fp8_f32(a, b, 0, false);
    w = (unsigned)__builtin_amdgcn_cvt_pk_fp8_f32(c, d, (int)w, true);
    return w;
}
__device__ __forceinline__ long mk64(unsigned lo, unsigned hi) {
    return (long)(((unsigned long long)hi << 32) | (unsigned long long)lo);
}
__device__ __forceinline__ void async16(void* lds_uniform, const void* gsrc) {
    __builtin_amdgcn_global_load_lds(
        (__attribute__((address_space(1))) void*)(gsrc),
        (__attribute__((address_space(3))) void*)(lds_uniform),
        16, 0, 0);
}

// ---------------------------------------------------------------------------
// prep: byte-identical to R17/R18 (MX sigma mapping, verified absmax 0.125).
// ---------------------------------------------------------------------------

__global__ void prep_kernel(const float* __restrict__ W1, const float* __restrict__ b1,
                            const float* __restrict__ W2, const float* __restrict__ b2,
                            const float* __restrict__ W3, const float* __restrict__ b3,
                            __bf16* __restrict__ w1p, uint2* __restrict__ w2p,
                            uint2* __restrict__ w3c)
{
    int idx = blockIdx.x * blockDim.x + threadIdx.x;
    if (idx < 1664) {
        int lane = idx & 63;
        int nt = idx >> 6;
        int rho = lane & 15, g = lane >> 4;
        int kap = (nt < 24)
            ? 128 * (nt >> 3) + 32 * (rho >> 2) + 4 * (nt & 7) + (rho & 3)
            : 384 + 8 * (rho >> 2) + 4 * (nt & 1) + (rho & 3);
        bf16x8 v;
        #pragma unroll
        for (int j = 0; j < 8; ++j) {
            int k = g * 8 + j;
            float x = 0.f;
            if (kap < 400) {
                if (k < 17) x = W1[kap * 17 + k];
                else if (k == 17) x = b1[kap];
            } else if (kap == 400) {
                if (k == 17) x = 1.0f;
            }
            v[j] = (__bf16)x;
        }
        *(bf16x8*)(w1p + idx * 8) = v;
    } else if (idx < 1664 + 16640) {
        int i2 = idx - 1664;
        int fg = i2 >> 6, lane = i2 & 63;
        int q = fg / 65, rem = fg % 65;
        int t = rem / 13, kt = rem % 13;
        int c16 = lane & 15, g = lane >> 4;
        int local = t * 16 + c16;
        int ff = q * 79 + local;
        int within, kbase;
        if (kt < 12) {
            int m = kt >> 2, u = kt & 3;
            kbase = 128 * m + 32 * g + 8 * u;
            within = m * 256 + lane * 4 + u;
        } else {
            kbase = 384 + g * 8;
            within = 768 + lane;
        }
        float v[8];
        #pragma unroll
        for (int j = 0; j < 8; ++j) {
            int kap = kbase + j;
            float x = 0.f;
            if (local == 79) {
                x = (kap == 400) ? 1.0f : 0.f;
            } else if (local < 79 && ff < 300) {
                if (kap < 400) x = W2[ff * 400 + kap];
                else if (kap == 400) x = b2[ff];
            }
            v[j] = x;
        }
        uint2 d;
        d.x = pkword(v[0], v[1], v[2], v[3]);
        d.y = pkword(v[4], v[5], v[6], v[7]);
        w2p[(q * 5 + t) * 832 + within] = d;
    } else if (idx < 1664 + 16640 + 768) {
        int i3 = idx - 1664 - 16640;
        int fg = i3 >> 6, lane = i3 & 63;
        int q = fg / 3, k2 = fg % 3;
        int o = lane & 15, g = lane >> 4;
        float v[8];
        #pragma unroll
        for (int j = 0; j < 8; ++j) {
            int t2  = 2 * k2 + (j >> 2);
            int rho = g * 4 + (j & 3);
            int local = t2 * 16 + rho;
            float x = 0.f;
            if (o < 5 && t2 < 5) {
                if (local == 79) x = b3[o] * 0.25f;
                else if (local < 79 && q * 79 + local < 300)
                    x = W3[o * 300 + q * 79 + local];
            }
            v[j] = x;
        }
        uint2 d;
        d.x = pkword(v[0], v[1], v[2], v[3]);
        d.y = pkword(v[4], v[5], v[6], v[7]);
        w3c[i3] = d;
    }
}

// ---------------------------------------------------------------------------
// Actor R20 = R18 + coalesced per-wave state staging:
// each wave f32x4-loads its own 32 contiguous state rows (2176B, 16B-aligned,
// ISSUED FIRST so the dependent ds_write's vmcnt wait doesn't drain the W2
// staging queue) into LDS, then builds sb via same-wave ds_reads (no barrier
// needed). Replaces the branch-selected stride-68B scalar gather from
// fill-flushed cold HBM. Everything else identical to R18 (25.33us,
// absmax 0.125): whole W2p in LDS, ONE barrier, independent waves.
// ---------------------------------------------------------------------------
__global__ __launch_bounds__(512, 2)
void actor_kernel(const float* __restrict__ state,
                  const __bf16* __restrict__ w1p,
                  const uint2* __restrict__ w2p,
                  const uint2* __restrict__ w3c,
                  float* __restrict__ out)
{
    __shared__ __align__(32) char  s_w2[133120];   // entire W2p, read-only after B1
    __shared__ __align__(16) float s_st[8][544];   // 17,408B per-wave state rows

    const int tid = threadIdx.x;
    const int wid = tid >> 6;            // 8 waves: rows wid*32..+31
    const int ln  = tid & 63;
    const int g   = ln >> 4, c16 = ln & 15;
    const int brow = (blockIdx.x << 8) + wid * 32;   // 256 rows/block

    // ---- coalesced state staging: 136 f32x4 per wave, issued FIRST ----
    {
        const float* wbase = state + brow * 17;      // 16B aligned (brow % 32 == 0)
        float* dst = &s_st[wid][0];
        #pragma unroll
        for (int i = 0; i < 3; ++i) {
            int idx = ln + i * 64;
            if (idx < 136) {
                f32x4 v = *(const f32x4*)(wbase + idx * 4);
                *(f32x4*)(dst + idx * 4) = v;
            }
        }
    }

    // ---- stage ALL W2p -> LDS (130 x 1KB chunks, 8-wave stride) ----
    {
        const char* gb = (const char*)w2p;
        for (int i = wid; i < 130; i += 8)
            async16(s_w2 + i * 1024, gb + i * 1024 + ln * 16);
    }

    // ---- hoisted W3 fragment loads (L2-hot) ----
    long w3r[4][3];
    {
        const long* gw3 = (const long*)w3c;
        #pragma unroll
        for (int q = 0; q < 4; ++q)
            #pragma unroll
            for (int k2 = 0; k2 < 3; ++k2)
                w3r[q][k2] = gw3[(q * 3 + k2) * 64 + ln];
    }

    // ---- build state A-frags from LDS (same-wave write->read, no barrier) ----
    bf16x8 sbA, sbB;
    {
        const float* rpA = &s_st[wid][0] + c16 * 17;
        const float* rpB = rpA + 16 * 17;
        if (g < 2) {
            #pragma unroll
            for (int j = 0; j < 8; ++j) {
                sbA[j] = (__bf16)rpA[g * 8 + j];
                sbB[j] = (__bf16)rpB[g * 8 + j];
            }
        } else if (g == 2) {
            sbA[0] = (__bf16)rpA[16]; sbB[0] = (__bf16)rpB[16];
            sbA[1] = (__bf16)1.0f;    sbB[1] = (__bf16)1.0f;   // bias carrier k=17
            #pragma unroll
            for (int j = 2; j < 8; ++j) { sbA[j] = (__bf16)0.f; sbB[j] = (__bf16)0.f; }
        } else {
            #pragma unroll
            for (int j = 0; j < 8; ++j) { sbA[j] = (__bf16)0.f; sbB[j] = (__bf16)0.f; }
        }
    }

    // ---- Phase A from L2-resident w1p: h1 as MX B-frags + K=32 tail ----
    int8v fmA[3], fmB[3];
    long fr12A, fr12B;
    {
        #pragma unroll
        for (int m = 0; m < 3; ++m)
            #pragma unroll
            for (int j = 0; j < 8; ++j) {
                int nt = m * 8 + j;
                bf16x8 w = *(const bf16x8*)(w1p + (nt * 64 + ln) * 8);
                f32x4 aA = {0.f,0.f,0.f,0.f}, aB = {0.f,0.f,0.f,0.f};
                aA = __builtin_amdgcn_mfma_f32_16x16x32_bf16(w, sbA, aA, 0, 0, 0);
                aB = __builtin_amdgcn_mfma_f32_16x16x32_bf16(w, sbB, aB, 0, 0, 0);
                fmA[m][j] = (int)pkword(lrelu(aA[0]), lrelu(aA[1]), lrelu(aA[2]), lrelu(aA[3]));
                fmB[m][j] = (int)pkword(lrelu(aB[0]), lrelu(aB[1]), lrelu(aB[2]), lrelu(aB[3]));
            }
        unsigned dA[2], dB[2];
        #pragma unroll
        for (int h = 0; h < 2; ++h) {
            int nt = 24 + h;
            bf16x8 w = *(const bf16x8*)(w1p + (nt * 64 + ln) * 8);
            f32x4 aA = {0.f,0.f,0.f,0.f}, aB = {0.f,0.f,0.f,0.f};
            aA = __builtin_amdgcn_mfma_f32_16x16x32_bf16(w, sbA, aA, 0, 0, 0);
            aB = __builtin_amdgcn_mfma_f32_16x16x32_bf16(w, sbB, aB, 0, 0, 0);
            dA[h] = pkword(lrelu(aA[0]), lrelu(aA[1]), lrelu(aA[2]), lrelu(aA[3]));
            dB[h] = pkword(lrelu(aB[0]), lrelu(aB[1]), lrelu(aB[2]), lrelu(aB[3]));
        }
        fr12A = mk64(dA[0], dA[1]);
        fr12B = mk64(dB[0], dB[1]);
    }

    __syncthreads();   // THE barrier: W2 staged; nothing syncs after

    // ---- 4 quarters, fully independent per wave (LDS read-only) ----
    f32x4 ccsA = {0.f, 0.f, 0.f, 0.f};
    f32x4 ccsB = {0.f, 0.f, 0.f, 0.f};

    #pragma unroll 1
    for (int q = 0; q < 4; ++q) {
        const char* bufp = s_w2 + q * 33280;
        unsigned wdA[5], wdB[5];
        #pragma unroll
        for (int t = 0; t < 5; ++t) {
            const char* bt = bufp + t * 6656;
            f32x4 aA = {0.f,0.f,0.f,0.f}, aB = {0.f,0.f,0.f,0.f};
            #pragma unroll
            for (int m = 0; m < 3; ++m) {
                int8v wf = *(const int8v*)(bt + m * 2048 + ln * 32);
                aA = __builtin_amdgcn_mfma_scale_f32_16x16x128_f8f6f4(
                         wf, fmA[m], aA, 0, 0, 0, SCL1, 0, SCL1);
                aB = __builtin_amdgcn_mfma_scale_f32_16x16x128_f8f6f4(
                         wf, fmB[m], aB, 0, 0, 0, SCL1, 0, SCL1);
            }
            long p12 = *(const long*)(bt + 6144 + ln * 8);
            aA = __builtin_amdgcn_mfma_f32_16x16x32_fp8_fp8(p12, fr12A, aA, 0, 0, 0);
            aB = __builtin_amdgcn_mfma_f32_16x16x32_fp8_fp8(p12, fr12B, aB, 0, 0, 0);
            wdA[t] = pkword(lrelu(aA[0]), lrelu(aA[1]), lrelu(aA[2]), lrelu(aA[3]));
            wdB[t] = pkword(lrelu(aB[0]), lrelu(aB[1]), lrelu(aB[2]), lrelu(aB[3]));
        }
        {
            f32x4 cc = {0.f, 0.f, 0.f, 0.f};
            cc = __builtin_amdgcn_mfma_f32_16x16x32_fp8_fp8(w3r[q][0], mk64(wdA[0], wdA[1]), cc, 0, 0, 0);
            cc = __builtin_amdgcn_mfma_f32_16x16x32_fp8_fp8(w3r[q][1], mk64(wdA[2], wdA[3]), cc, 0, 0, 0);
            cc = __builtin_amdgcn_mfma_f32_16x16x32_fp8_fp8(w3r[q][2], mk64(wdA[4], 0u),     cc, 0, 0, 0);
            ccsA += cc;
        }
        {
            f32x4 cc = {0.f, 0.f, 0.f, 0.f};
            cc = __builtin_amdgcn_mfma_f32_16x16x32_fp8_fp8(w3r[q][0], mk64(wdB[0], wdB[1]), cc, 0, 0, 0);
            cc = __builtin_amdgcn_mfma_f32_16x16x32_fp8_fp8(w3r[q][1], mk64(wdB[2], wdB[3]), cc, 0, 0, 0);
            cc = __builtin_amdgcn_mfma_f32_16x16x32_fp8_fp8(w3r[q][2], mk64(wdB[4], 0u),     cc, 0, 0, 0);
            ccsB += cc;
        }
    }

    // ---- Epilogue: 32 lanes/wave solve QP for 32 rows ----
    float tA4 = __shfl_xor(ccsA[0], 16);
    float sB0 = __shfl_xor(ccsB[0], 16);
    float sB1 = __shfl_xor(ccsB[1], 16);
    float sB2 = __shfl_xor(ccsB[2], 16);
    float sB3 = __shfl_xor(ccsB[3], 16);

    if (ln < 32) {
        float v[5];
        if (ln < 16) {
            v[0] = -lrelu(ccsA[0]); v[1] = -lrelu(ccsA[1]);
            v[2] = -lrelu(ccsA[2]); v[3] = -lrelu(ccsA[3]);
            v[4] = -lrelu(tA4);
        } else {
            v[0] = -lrelu(sB0); v[1] = -lrelu(sB1);
            v[2] = -lrelu(sB2); v[3] = -lrelu(sB3);
            v[4] = -lrelu(ccsB[0]);
        }

        float bp[10];
        #pragma unroll
        for (int i = 0; i < 5; ++i) { bp[i] = v[i]; bp[i + 5] = v[i] - UBV; }
        float blo = -1e30f, glo = 0.f;
        #pragma unroll
        for (int j = 0; j < 10; ++j) {
            float b = bp[j];
            float gsum = 0.f;
            #pragma unroll
            for (int i = 0; i < 5; ++i) {
                float zc = v[i] - b;
                zc = fminf(fmaxf(zc, 0.f), UBV);
                gsum += zc;
            }
            if (gsum >= SUMC && b > blo) { blo = b; glo = gsum; }
        }
        float bhi = 1e30f;
        #pragma unroll
        for (int j = 0; j < 10; ++j) {
            float b = bp[j];
            if (b > blo && b < bhi) bhi = b;
        }
        float mid = 0.5f * (blo + bhi);
        int nfree = 0;
        #pragma unroll
        for (int i = 0; i < 5; ++i)
            nfree += (v[i] > mid && v[i] < mid + UBV) ? 1 : 0;
        float nu = (nfree > 0) ? blo + (glo - SUMC) / (float)nfree : blo;

        int row = brow + ln;
        #pragma unroll
        for (int o = 0; o < 5; ++o) {
            float zf = v[o] - nu;
            zf = fminf(fmaxf(zf, 0.f), UBV);
            out[row * 5 + o] = zf;
        }
    }
}

extern "C" void kernel_launch(void* const* d_in, const int* in_sizes, int n_in,
                              void* d_out, int out_size, void* d_ws, size_t ws_size,
                              hipStream_t stream) {
    const float* state = (const float*)d_in[0];
    const float* W1    = (const float*)d_in[1];
    const float* b1    = (const float*)d_in[2];
    const float* W2    = (const float*)d_in[3];
    const float* b2    = (const float*)d_in[4];
    const float* W3    = (const float*)d_in[5];
    const float* b3    = (const float*)d_in[6];
    float* out = (float*)d_out;

    char* base = (char*)d_ws;
    __bf16* w1p = (__bf16*)base;                   // 26,624B
    uint2*  w2p = (uint2*)(base + 26624);          // 133,120B
    uint2*  w3c = (uint2*)(base + 26624 + 133120); // 6,144B

    const int total = 1664 + 16640 + 768;
    prep_kernel<<<(total + 255) / 256, 256, 0, stream>>>(W1, b1, W2, b2, W3, b3,
                                                         w1p, w2p, w3c);

    int B = in_sizes[0] / 17;                      // 65536
    actor_kernel<<<B / 256, 512, 0, stream>>>(state, w1p, w2p, w3c, out);
}